// Round 1
// 335.000 us; speedup vs baseline: 1.0018x; 1.0018x over previous
//
#include <hip/hip_runtime.h>

#define BATCH   4
#define SEQLEN  4096
#define NHEADS  32
#define PDIM    64
#define NDIM    16
#define CHUNK   64
#define NCHUNK  64   // SEQLEN / CHUNK

typedef short v8s __attribute__((ext_vector_type(8)));
typedef float v4f __attribute__((ext_vector_type(4)));

__device__ __forceinline__ short f2bf(float f) {
    union { float f; unsigned u; } x; x.f = f;
    unsigned r = (x.u + 0x7FFFu + ((x.u >> 16) & 1u)) >> 16;  // RNE
    return (short)r;
}
__device__ __forceinline__ float bf2f(short s) {
    union { unsigned u; float f; } x; x.u = ((unsigned)(unsigned short)s) << 16;
    return x.f;
}

// Wave-64 inclusive scan, Hillis-Steele: 6 shuffle steps (~200 cyc) replaces
// the old 64-iteration dependent LDS-read chain (~7700 cyc critical path).
__device__ __forceinline__ float wave_iscan(float v, int lane) {
#pragma unroll
    for (int d = 1; d < 64; d <<= 1) {
        float o = __shfl_up(v, (unsigned)d, 64);
        if (lane >= d) v += o;
    }
    return v;
}

// ---------------------------------------------------------------------------
// Kernel 1 (v3, MFMA): states[p,n] = sum_t (dec_t*X[t,p]) * B[t,n]
// Changes vs v2: wave-parallel cumsum (wave 0, pre-barrier), A-frags built
// per-wave directly from sXraw (no aF LDS round-trip), barriers 4 -> 1,
// LDS 27.6KB -> ~19KB (8 blocks/CU).
// ---------------------------------------------------------------------------
__global__ __launch_bounds__(256) void k_states(
    const float* __restrict__ X, const float* __restrict__ A,
    const float* __restrict__ Bm, float* __restrict__ states,
    float* __restrict__ csum)
{
    const int cc = blockIdx.x, hh = blockIdx.y, bb = blockIdx.z;
    const int tid = threadIdx.x;
    const int lane = tid & 63, W = tid >> 6;
    const int t0 = bb * SEQLEN + cc * CHUNK;

    __shared__ __align__(16) float sXraw[CHUNK][PDIM + 1];  // 16.6 KB
    __shared__ __align__(16) short bF[1024];  // B b-frags [kk*64+lane][8]
    __shared__ float sDec[CHUNK];

    {   // X raw tile, coalesced float4
        const int sb = tid >> 4, p4 = (tid & 15) * 4;
        for (int i = 0; i < 4; ++i) {
            int s = sb + i * 16;
            const float4 v = *(const float4*)&X[((size_t)(t0 + s) * NHEADS + hh) * PDIM + p4];
            sXraw[s][p4]     = v.x; sXraw[s][p4 + 1] = v.y;
            sXraw[s][p4 + 2] = v.z; sXraw[s][p4 + 3] = v.w;
        }
    }
    {   // B -> b-frag layout: elem B[t][n] at (( (t>>5)*64 + ((t>>3)&3)*16 + n )*8 + (t&7))
        const int r = tid >> 2, n0 = (tid & 3) * 4;
        float4 bv = *(const float4*)&Bm[((size_t)(t0 + r) * NHEADS + hh) * NDIM + n0];
        const int kk = r >> 5, q = (r >> 3) & 3, j = r & 7;
        const int base = (kk * 64 + q * 16) * 8 + j;
        bF[base + (n0 + 0) * 8] = f2bf(bv.x);
        bF[base + (n0 + 1) * 8] = f2bf(bv.y);
        bF[base + (n0 + 2) * 8] = f2bf(bv.z);
        bF[base + (n0 + 3) * 8] = f2bf(bv.w);
    }
    if (tid < 64) {   // wave 0: cumsum(A) via shuffle scan, overlaps staging above
        float a = A[(t0 + tid) * NHEADS + hh];
        float v = wave_iscan(a, lane);
        float tot = __shfl(v, 63, 64);
        sDec[tid] = __expf(tot - v);
        if (tid == 0) csum[(bb * NHEADS + hh) * NCHUNK + cc] = tot;
    }
    __syncthreads();   // the only barrier

    // Each wave builds its own A-frags straight from sXraw (column reads,
    // conflict-free via +1 pad): frag elem (lane,j) = Xw^T[W*16+(lane&15)][kk*32+(lane>>4)*8+j]
    const int m = lane & 15, q = lane >> 4;
    v8s a0, a1;
#pragma unroll
    for (int j = 0; j < 8; ++j) {
        const int tr = q * 8 + j;
        a0[j] = f2bf(sXraw[tr][W * 16 + m] * sDec[tr]);
        a1[j] = f2bf(sXraw[32 + tr][W * 16 + m] * sDec[32 + tr]);
    }
    v8s b0 = *(const v8s*)&bF[(0 * 64 + lane) * 8];
    v8s b1 = *(const v8s*)&bF[(1 * 64 + lane) * 8];
    const v4f zero = {0.f, 0.f, 0.f, 0.f};
    v4f acc = __builtin_amdgcn_mfma_f32_16x16x32_bf16(a0, b0, zero, 0, 0, 0);
    acc = __builtin_amdgcn_mfma_f32_16x16x32_bf16(a1, b1, acc, 0, 0, 0);

    const int n = lane & 15;
    float* sp = states + ((size_t)(bb * NHEADS + hh) * NCHUNK + cc) * (PDIM * NDIM);
#pragma unroll
    for (int r = 0; r < 4; ++r)
        sp[(W * 16 + q * 4 + r) * NDIM + n] = acc[r];
}

// ---------------------------------------------------------------------------
// Kernel 2 (v2): batch-register scan. All 64 chunk-values per (p,n) element
// loaded into registers up front (independent, pipelined), serial FMA chain
// in regs, then 64 stores.
// ---------------------------------------------------------------------------
__global__ __launch_bounds__(256) void k_scan(
    float* __restrict__ states, const float* __restrict__ csum)
{
    const int bh = blockIdx.y;
    const int el = blockIdx.x * 256 + threadIdx.x;
    __shared__ float sE[NCHUNK];
    if (threadIdx.x < NCHUNK) sE[threadIdx.x] = __expf(csum[bh * NCHUNK + threadIdx.x]);
    __syncthreads();
    float* base = states + (size_t)bh * NCHUNK * (PDIM * NDIM) + el;
    float v[NCHUNK];
#pragma unroll
    for (int z = 0; z < NCHUNK; ++z) v[z] = base[z * (PDIM * NDIM)];
    float S = 0.f;
#pragma unroll
    for (int z = 0; z < NCHUNK; ++z) {
        const float nv = v[z];
        v[z] = S;
        S = sE[z] * S + nv;
    }
#pragma unroll
    for (int z = 0; z < NCHUNK; ++z) base[z * (PDIM * NDIM)] = v[z];
}

// ---------------------------------------------------------------------------
// Kernel 3 (v3): as round-2 MFMA output kernel, but the serial cumsum is
// replaced by the wave-0 shuffle scan, issued before the first barrier.
// ---------------------------------------------------------------------------
__global__ __launch_bounds__(256) void k_out(
    const float* __restrict__ X, const float* __restrict__ A,
    const float* __restrict__ Bm, const float* __restrict__ Cm,
    const float* __restrict__ states, float* __restrict__ Y)
{
    const int cc = blockIdx.x, hh = blockIdx.y, bb = blockIdx.z;
    const int tid = threadIdx.x;
    const int lane = tid & 63, W = tid >> 6;
    const int qq = lane >> 4, nn = lane & 15;
    const int t0 = bb * SEQLEN + cc * CHUNK;

    __shared__ __align__(16) char uBuf[CHUNK * (PDIM + 1) * 4];
    float (*sXraw)[PDIM + 1] = (float (*)[PDIM + 1])uBuf;
    short* gF = (short*)uBuf;
    __shared__ __align__(16) short xF[4096];
    __shared__ __align__(16) short cF[2048];
    __shared__ __align__(16) short bF[2048];
    __shared__ __align__(16) short sF[2048];
    __shared__ float sCum[CHUNK];

    {
        const int sb = tid >> 4, p4 = (tid & 15) * 4;
        for (int i = 0; i < 4; ++i) {
            int s = sb + i * 16;
            const float4 v = *(const float4*)&X[((size_t)(t0 + s) * NHEADS + hh) * PDIM + p4];
            sXraw[s][p4]     = v.x; sXraw[s][p4 + 1] = v.y;
            sXraw[s][p4 + 2] = v.z; sXraw[s][p4 + 3] = v.w;
        }
    }
    {
        const int r = tid >> 2, nn0 = (tid & 3) * 4;
        const int off = ((r >> 4) * 64 + (nn0 >> 3) * 16 + (r & 15)) * 8 + (nn0 & 7);
        float4 cv = *(const float4*)&Cm[((size_t)(t0 + r) * NHEADS + hh) * NDIM + nn0];
        cF[off] = f2bf(cv.x); cF[off + 1] = f2bf(cv.y);
        cF[off + 2] = f2bf(cv.z); cF[off + 3] = f2bf(cv.w);
        float4 bv = *(const float4*)&Bm[((size_t)(t0 + r) * NHEADS + hh) * NDIM + nn0];
        bF[off] = f2bf(bv.x); bF[off + 1] = f2bf(bv.y);
        bF[off + 2] = f2bf(bv.z); bF[off + 3] = f2bf(bv.w);
        const float* sp = states + ((size_t)(bb * NHEADS + hh) * NCHUNK + cc) * (PDIM * NDIM)
                                 + r * NDIM + nn0;
        float4 sv = *(const float4*)sp;
        sF[off] = f2bf(sv.x); sF[off + 1] = f2bf(sv.y);
        sF[off + 2] = f2bf(sv.z); sF[off + 3] = f2bf(sv.w);
    }
    {
        const v8s z8 = {0, 0, 0, 0, 0, 0, 0, 0};
        for (int z = tid; z < 384; z += 256) {
            short* base = (z < 128) ? cF : (z < 256) ? bF : sF;
            int idx = z & 127;
            int off = (idx >> 5) * 512 + 256 + (idx & 31) * 8;
            *(v8s*)&base[off] = z8;
        }
    }
    if (tid < 64) {   // wave 0: cumsum(A) via shuffle scan, overlaps staging
        float a = A[(t0 + tid) * NHEADS + hh];
        sCum[tid] = wave_iscan(a, lane);
    }
    __syncthreads();

    for (int c = tid; c < 512; c += 256) {
        int cn = c & 15, cq = (c >> 4) & 3, nt = (c >> 6) & 3, kk = c >> 8;
        int srow = kk * 32 + cq * 8, p = nt * 16 + cn;
        v8s v;
        for (int j = 0; j < 8; ++j) v[j] = f2bf(sXraw[srow + j][p]);
        *(v8s*)&xF[c * 8] = v;
    }
    __syncthreads();

    const v8s cfrag = *(const v8s*)&cF[(W * 64 + lane) * 8];
    const v4f zero = {0.f, 0.f, 0.f, 0.f};
    for (int st = 0; st < 4; ++st) {
        const int kk = st >> 1, q2 = (st & 1) * 2 + (nn >> 3), j2 = nn & 7;
        if (st <= W) {
            v8s bfrag = *(const v8s*)&bF[(st * 64 + lane) * 8];
            v4f acc = __builtin_amdgcn_mfma_f32_16x16x32_bf16(cfrag, bfrag, zero, 0, 0, 0);
            const int s = st * 16 + nn;
            const float cums = sCum[s];
            for (int r = 0; r < 4; ++r) {
                int t = W * 16 + qq * 4 + r;
                float g = (t >= s) ? acc[r] * __expf(sCum[t] - cums) : 0.f;
                gF[((W * 2 + kk) * 64 + q2 * 16 + qq * 4 + r) * 8 + j2] = f2bf(g);
            }
        } else if (kk == 0 || W >= 2) {
            for (int r = 0; r < 4; ++r)
                gF[((W * 2 + kk) * 64 + q2 * 16 + qq * 4 + r) * 8 + j2] = 0;
        }
    }
    const float et = __expf(sCum[W * 16 + nn]);
    v8s cefrag;
    for (int j = 0; j < 8; ++j) cefrag[j] = f2bf(bf2f(cfrag[j]) * et);
    __syncthreads();

    const v8s ga0 = *(const v8s*)&gF[((W * 2 + 0) * 64 + lane) * 8];
    const bool usekk1 = (W >= 2);
    v8s ga1 = {0, 0, 0, 0, 0, 0, 0, 0};
    if (usekk1) ga1 = *(const v8s*)&gF[((W * 2 + 1) * 64 + lane) * 8];
    v4f acc[4];
    for (int nt = 0; nt < 4; ++nt) {
        v8s sfrag = *(const v8s*)&sF[(nt * 64 + lane) * 8];
        v4f a = __builtin_amdgcn_mfma_f32_16x16x32_bf16(cefrag, sfrag, zero, 0, 0, 0);
        v8s x0 = *(const v8s*)&xF[((0 * 4 + nt) * 64 + lane) * 8];
        a = __builtin_amdgcn_mfma_f32_16x16x32_bf16(ga0, x0, a, 0, 0, 0);
        if (usekk1) {
            v8s x1 = *(const v8s*)&xF[((1 * 4 + nt) * 64 + lane) * 8];
            a = __builtin_amdgcn_mfma_f32_16x16x32_bf16(ga1, x1, a, 0, 0, 0);
        }
        acc[nt] = a;
    }
    for (int r = 0; r < 4; ++r) {
        int t = W * 16 + qq * 4 + r;
        float* yp = Y + ((size_t)(t0 + t) * NHEADS + hh) * PDIM + nn;
        for (int nt = 0; nt < 4; ++nt) yp[nt * 16] = acc[nt][r];
    }
}

// ---------------------------------------------------------------------------
extern "C" void kernel_launch(void* const* d_in, const int* in_sizes, int n_in,
                              void* d_out, int out_size, void* d_ws, size_t ws_size,
                              hipStream_t stream) {
    const float* X  = (const float*)d_in[0];
    const float* A  = (const float*)d_in[1];
    const float* Bm = (const float*)d_in[2];
    const float* Cm = (const float*)d_in[3];
    float* Y = (float*)d_out;

    float* states = (float*)d_ws;
    float* csum   = states + (size_t)BATCH * NHEADS * NCHUNK * PDIM * NDIM;

    dim3 grid(NCHUNK, NHEADS, BATCH);
    k_states<<<grid, 256, 0, stream>>>(X, A, Bm, states, csum);
    dim3 gscan(4, BATCH * NHEADS, 1);
    k_scan<<<gscan, 256, 0, stream>>>(states, csum);
    k_out<<<grid, 256, 0, stream>>>(X, A, Bm, Cm, states, Y);
}